// Round 2
// baseline (3404.189 us; speedup 1.0000x reference)
//
#include <hip/hip_runtime.h>
#include <stdint.h>

// All-fp32 pipeline (bf16 fails: LN amplifies attention error x55, tan(delta)
// physics is chaotic near |delta|=pi/2 -> need fp32-accurate delta).

__device__ __forceinline__ float readlane_f(float v, int lane) {
  return __uint_as_float(__builtin_amdgcn_readlane(__float_as_uint(v), lane));
}

// ---------------------------------------------------------------------------
// Kernel A: fused QKV projection (fp32). obs(8192x128) @ {Wq,Wk,Wv}(128x512)+b
// grid (12, 256): cb = blockIdx.x (0..11): which = cb>>2, col0 = (cb&3)*128
// ---------------------------------------------------------------------------
__global__ __launch_bounds__(256) void qkv_f32(
    const float* __restrict__ obs,
    const float* __restrict__ Wq, const float* __restrict__ bq,
    const float* __restrict__ Wk, const float* __restrict__ bk,
    const float* __restrict__ Wv, const float* __restrict__ bv,
    float* __restrict__ Qf, float* __restrict__ Kf, float* __restrict__ Vf)
{
  __shared__ float smA[32][128];
  __shared__ float smB[64][128];
  const int t  = threadIdx.x;
  const int cb = blockIdx.x;
  const int rb = blockIdx.y;
  const float* W; const float* bias; float* Op;
  if (cb < 4)      { W = Wq; bias = bq; Op = Qf; }
  else if (cb < 8) { W = Wk; bias = bk; Op = Kf; }
  else             { W = Wv; bias = bv; Op = Vf; }
  const int col0 = (cb & 3) * 128;

  {
    const float4* src = (const float4*)(obs + (size_t)rb * (32 * 128));
    float4* dst = (float4*)&smA[0][0];
#pragma unroll
    for (int i = 0; i < 4; ++i) dst[i * 256 + t] = src[i * 256 + t];
  }

  const int tr = t >> 5, tc = t & 31;
  float acc[4][4] = {};
#pragma unroll 1
  for (int kc = 0; kc < 2; ++kc) {
    __syncthreads();
#pragma unroll
    for (int i = 0; i < 8; ++i) {
      int id = i * 256 + t;
      int kr = id >> 5, c4 = id & 31;
      *(float4*)&smB[kr][c4 * 4] =
          *(const float4*)(W + (size_t)(kc * 64 + kr) * 512 + col0 + c4 * 4);
    }
    __syncthreads();
#pragma unroll 4
    for (int k2 = 0; k2 < 64; ++k2) {
      float4 b = *(const float4*)&smB[k2][tc * 4];
      float a0 = smA[tr * 4 + 0][kc * 64 + k2];
      float a1 = smA[tr * 4 + 1][kc * 64 + k2];
      float a2 = smA[tr * 4 + 2][kc * 64 + k2];
      float a3 = smA[tr * 4 + 3][kc * 64 + k2];
#pragma unroll
      for (int j = 0; j < 4; ++j) {
        acc[0][j] += a0 * b[j];
        acc[1][j] += a1 * b[j];
        acc[2][j] += a2 * b[j];
        acc[3][j] += a3 * b[j];
      }
    }
  }

  float4 bb = *(const float4*)(bias + col0 + tc * 4);
  const int r0 = rb * 32 + tr * 4;
#pragma unroll
  for (int ii = 0; ii < 4; ++ii) {
    float4 o;
#pragma unroll
    for (int j = 0; j < 4; ++j) o[j] = acc[ii][j] + bb[j];
    *(float4*)(Op + (size_t)(r0 + ii) * 512 + col0 + tc * 4) = o;
  }
}

// ---------------------------------------------------------------------------
// Kernel B: fp32 flash attention.
// 256 blocks x 256 threads. Block = 32 q-rows; wave ty owns rows ty*8..+7.
// Q resident in regs qreg[8][8] (row ty*8+i, d = u*64+tx), broadcast via
// v_readlane. K staged key-major [256][17] (odd stride: conflict-free),
// V chunks [8][512] reuse the same 17KB LDS. P stays in registers; PV also
// fetches P via readlane. Online softmax in fp32 (always-rescale, no defer).
// ---------------------------------------------------------------------------
__global__ __launch_bounds__(256, 2) void flash_f32(
    const float* __restrict__ Q, const float* __restrict__ K,
    const float* __restrict__ V, float* __restrict__ Out)
{
  __shared__ __align__(16) float KV[4352];   // max(256*17, 8*512) floats
  const int t  = threadIdx.x;
  const int tx = t & 63;
  const int ty = t >> 6;
  const int qrow0 = blockIdx.x * 32;
  const float sc = 0.04419417382415922f;     // 1/sqrt(512)

  float qreg[8][8];
#pragma unroll
  for (int i = 0; i < 8; ++i)
#pragma unroll
    for (int u = 0; u < 8; ++u)
      qreg[i][u] = Q[(size_t)(qrow0 + ty * 8 + i) * 512 + u * 64 + tx];

  float O[8][8];
#pragma unroll
  for (int i = 0; i < 8; ++i)
#pragma unroll
    for (int n = 0; n < 8; ++n) O[i][n] = 0.f;
  float m[8], l[8];
#pragma unroll
  for (int i = 0; i < 8; ++i) { m[i] = -1e30f; l[i] = 0.f; }

#pragma unroll 1
  for (int kt = 0; kt < 32; ++kt) {          // 32 key-tiles of 256
    float p[8][4];
#pragma unroll
    for (int i = 0; i < 8; ++i)
#pragma unroll
      for (int j = 0; j < 4; ++j) p[i][j] = 0.f;

    // ---- S = Q.K^T over d, chunks of 16 ----
#pragma unroll
    for (int u = 0; u < 8; ++u) {
#pragma unroll 1
      for (int ds = 0; ds < 4; ++ds) {
        const int D0 = u * 64 + ds * 16;
        __syncthreads();
        {
          const int dq = t & 3, keyi = t >> 2;
#pragma unroll
          for (int pass = 0; pass < 4; ++pass) {
            const int key = pass * 64 + keyi;
            float4 g = *(const float4*)(K + (size_t)(kt * 256 + key) * 512 + D0 + dq * 4);
            KV[key * 17 + dq * 4 + 0] = g.x;
            KV[key * 17 + dq * 4 + 1] = g.y;
            KV[key * 17 + dq * 4 + 2] = g.z;
            KV[key * 17 + dq * 4 + 3] = g.w;
          }
        }
        __syncthreads();
#pragma unroll
        for (int dd = 0; dd < 16; ++dd) {
          float qs[8];
#pragma unroll
          for (int i = 0; i < 8; ++i) qs[i] = readlane_f(qreg[i][u], ds * 16 + dd);
          float kv[4];
#pragma unroll
          for (int j = 0; j < 4; ++j) kv[j] = KV[(j * 64 + tx) * 17 + dd];
#pragma unroll
          for (int i = 0; i < 8; ++i)
#pragma unroll
            for (int j = 0; j < 4; ++j)
              p[i][j] = fmaf(qs[i], kv[j], p[i][j]);
        }
      }
    }

    // ---- online softmax (rows are wave-private; lane = key slice) ----
#pragma unroll
    for (int i = 0; i < 8; ++i) {
      float rmax = -1e30f;
#pragma unroll
      for (int j = 0; j < 4; ++j) { p[i][j] *= sc; rmax = fmaxf(rmax, p[i][j]); }
#pragma unroll
      for (int o = 1; o < 64; o <<= 1) rmax = fmaxf(rmax, __shfl_xor(rmax, o));
      float mn = fmaxf(m[i], rmax);
      float corr = __expf(m[i] - mn);
      m[i] = mn;
      float ps = 0.f;
#pragma unroll
      for (int j = 0; j < 4; ++j) { float e = __expf(p[i][j] - mn); p[i][j] = e; ps += e; }
#pragma unroll
      for (int o = 1; o < 64; o <<= 1) ps += __shfl_xor(ps, o);
      l[i] = l[i] * corr + ps;
#pragma unroll
      for (int n = 0; n < 8; ++n) O[i][n] *= corr;
    }

    // ---- O += P.V, V in chunks of 8 keys ----
#pragma unroll
    for (int j = 0; j < 4; ++j) {
#pragma unroll 1
      for (int vc2 = 0; vc2 < 8; ++vc2) {
        __syncthreads();
        {
          const int kbase = kt * 256 + j * 64 + vc2 * 8;
#pragma unroll
          for (int pass = 0; pass < 4; ++pass) {
            const int idx = pass * 256 + t;
            const int row = idx >> 7;
            const int c4  = (idx & 127) * 4;
            *(float4*)&KV[row * 512 + c4] =
                *(const float4*)(V + (size_t)(kbase + row) * 512 + c4);
          }
        }
        __syncthreads();
#pragma unroll
        for (int kk = 0; kk < 8; ++kk) {
          float pvv[8];
#pragma unroll
          for (int i = 0; i < 8; ++i) pvv[i] = readlane_f(p[i][j], vc2 * 8 + kk);
          float vv[8];
#pragma unroll
          for (int n = 0; n < 8; ++n) vv[n] = KV[kk * 512 + n * 64 + tx];
#pragma unroll
          for (int i = 0; i < 8; ++i)
#pragma unroll
            for (int n = 0; n < 8; ++n)
              O[i][n] = fmaf(pvv[i], vv[n], O[i][n]);
        }
      }
    }
  }

  // epilogue: normalize and store
#pragma unroll
  for (int i = 0; i < 8; ++i) {
    float inv = 1.0f / l[i];
#pragma unroll
    for (int n = 0; n < 8; ++n)
      Out[(size_t)(qrow0 + ty * 8 + i) * 512 + n * 64 + tx] = O[i][n] * inv;
  }
}

// ---------------------------------------------------------------------------
// Kernel C: h = Out(8192x512) @ W1(512x512) + b1   (fp32 tiled)
// ---------------------------------------------------------------------------
__global__ __launch_bounds__(256) void mlp1_kernel(
    const float* __restrict__ X, const float* __restrict__ W1,
    const float* __restrict__ b1, float* __restrict__ Ho)
{
  __shared__ float smA[32][64];
  __shared__ float smB[64][128];
  const int t = threadIdx.x;
  const int cb = blockIdx.x;
  const int rb = blockIdx.y;
  const int col0 = cb * 128;
  const int tr = t >> 5, tc = t & 31;
  float acc[4][4] = {};
#pragma unroll 1
  for (int kc = 0; kc < 8; ++kc) {
    __syncthreads();
#pragma unroll
    for (int i = 0; i < 2; ++i) {
      int id = i * 256 + t;
      int r = id >> 4, c4 = id & 15;
      *(float4*)&smA[r][c4 * 4] =
          *(const float4*)(X + (size_t)(rb * 32 + r) * 512 + kc * 64 + c4 * 4);
    }
#pragma unroll
    for (int i = 0; i < 8; ++i) {
      int id = i * 256 + t;
      int kr = id >> 5, c4 = id & 31;
      *(float4*)&smB[kr][c4 * 4] =
          *(const float4*)(W1 + (size_t)(kc * 64 + kr) * 512 + col0 + c4 * 4);
    }
    __syncthreads();
#pragma unroll 4
    for (int k2 = 0; k2 < 64; ++k2) {
      float4 b = *(const float4*)&smB[k2][tc * 4];
      float a0 = smA[tr * 4 + 0][k2];
      float a1 = smA[tr * 4 + 1][k2];
      float a2 = smA[tr * 4 + 2][k2];
      float a3 = smA[tr * 4 + 3][k2];
#pragma unroll
      for (int j = 0; j < 4; ++j) {
        acc[0][j] += a0 * b[j];
        acc[1][j] += a1 * b[j];
        acc[2][j] += a2 * b[j];
        acc[3][j] += a3 * b[j];
      }
    }
  }
  const int r0 = rb * 32 + tr * 4;
  float4 bb = *(const float4*)(b1 + col0 + tc * 4);
#pragma unroll
  for (int ii = 0; ii < 4; ++ii) {
    float4 o;
#pragma unroll
    for (int j = 0; j < 4; ++j) o[j] = acc[ii][j] + bb[j];
    *(float4*)(Ho + (size_t)(r0 + ii) * 512 + col0 + tc * 4) = o;
  }
}

// ---------------------------------------------------------------------------
// Kernel D: per-row LayerNorm + ReLU + (512->2) head. One wave per row.
// ---------------------------------------------------------------------------
__global__ __launch_bounds__(256) void act_kernel(
    const float* __restrict__ H, const float* __restrict__ g1,
    const float* __restrict__ be1, const float* __restrict__ W2,
    const float* __restrict__ b2, float* __restrict__ act)
{
  const int lane = threadIdx.x & 63;
  const int w = threadIdx.x >> 6;
  const int row = blockIdx.x * 4 + w;
  const float* h = H + (size_t)row * 512;
  float x[8];
  *(float4*)&x[0] = *(const float4*)(h + lane * 8);
  *(float4*)&x[4] = *(const float4*)(h + lane * 8 + 4);
  float s = 0.f;
#pragma unroll
  for (int j = 0; j < 8; ++j) s += x[j];
#pragma unroll
  for (int o = 1; o < 64; o <<= 1) s += __shfl_xor(s, o);
  const float mu = s * (1.0f / 512.0f);
  float vs = 0.f;
#pragma unroll
  for (int j = 0; j < 8; ++j) { float d = x[j] - mu; vs += d * d; }
#pragma unroll
  for (int o = 1; o < 64; o <<= 1) vs += __shfl_xor(vs, o);
  const float rs = 1.0f / sqrtf(vs * (1.0f / 512.0f) + 1e-5f);
  float at = 0.f, ad = 0.f;
#pragma unroll
  for (int j = 0; j < 8; ++j) {
    int c = lane * 8 + j;
    float xn = (x[j] - mu) * rs * g1[c] + be1[c];
    xn = fmaxf(xn, 0.0f);
    at += xn * W2[2 * c];
    ad += xn * W2[2 * c + 1];
  }
#pragma unroll
  for (int o = 1; o < 64; o <<= 1) { at += __shfl_xor(at, o); ad += __shfl_xor(ad, o); }
  if (lane == 0) {
    act[row * 2 + 0] = at + b2[0];
    act[row * 2 + 1] = ad + b2[1];
  }
}

// ---------------------------------------------------------------------------
// Kernel E: 100-step bicycle model. Replicates jax op order exactly, incl.
// per-step yw = atan2(sin(yw), cos(yw)) wrap. f_load = 0 (C_A=C_R=0).
// ---------------------------------------------------------------------------
__global__ __launch_bounds__(256) void physics_kernel(
    const float* __restrict__ obs, const float* __restrict__ act,
    float* __restrict__ out)
{
  const int row = blockIdx.x * 256 + threadIdx.x;
  const float* o = obs + (size_t)row * 128;
  float xx = o[0] * 10.0f;
  float yy = o[1] * 10.0f;
  float vx = o[2] * 10.0f;
  float vy = o[3] * 10.0f;
  float yw = o[4] * 10.0f;
  float vv = sqrtf(vx * vx + vy * vy);
  const float th = act[row * 2 + 0];
  const float de = act[row * 2 + 1];
  const float dt_s = 0.001f;                 // np.float32(0.1/100)
  const float inv_wb = (float)(1.0 / 2.96);
  const float td = tanf(de);
#pragma unroll 1
  for (int i = 0; i < 100; ++i) {
    vv = vv + th * dt_s;
    float s1 = sinf(yw), c1 = cosf(yw);
    xx = xx + vv * c1 * dt_s;
    yy = yy + vv * s1 * dt_s;
    yw = yw + ((vv * td) * inv_wb) * dt_s;
    yw = atan2f(sinf(yw), cosf(yw));
  }
  float cf = cosf(yw), sf = sinf(yw);
  out[row * 5 + 0] = xx * 0.1f;
  out[row * 5 + 1] = yy * 0.1f;
  out[row * 5 + 2] = vv * cf * 0.1f;
  out[row * 5 + 3] = vv * sf * 0.1f;
  out[row * 5 + 4] = yw * 0.1f;
}

// ---------------------------------------------------------------------------
extern "C" void kernel_launch(void* const* d_in, const int* in_sizes, int n_in,
                              void* d_out, int out_size, void* d_ws, size_t ws_size,
                              hipStream_t stream) {
  const float* obs = (const float*)d_in[0];
  const float* Wq  = (const float*)d_in[1];
  const float* bq  = (const float*)d_in[2];
  const float* Wk  = (const float*)d_in[3];
  const float* bk  = (const float*)d_in[4];
  const float* Wv  = (const float*)d_in[5];
  const float* bv  = (const float*)d_in[6];
  const float* W1  = (const float*)d_in[7];
  const float* b1  = (const float*)d_in[8];
  const float* g1  = (const float*)d_in[9];
  const float* be1 = (const float*)d_in[10];
  const float* W2  = (const float*)d_in[11];
  const float* b2  = (const float*)d_in[12];

  char* ws = (char*)d_ws;
  float* Qf  = (float*)(ws);                         // [0,16M)
  float* Kf  = (float*)(ws + (size_t)(16 << 20));    // [16M,32M)
  float* Vf  = (float*)(ws + (size_t)(32 << 20));    // [32M,48M)
  float* Aout= (float*)(ws + (size_t)(48 << 20));    // [48M,64M)
  float* Ho  = (float*)(ws);                         // reuse [0,16M)
  float* Act = (float*)(ws + (size_t)(16 << 20));    // reuse [16M,+64K)
  float* out = (float*)d_out;

  qkv_f32<<<dim3(12, 256), 256, 0, stream>>>(obs, Wq, bq, Wk, bk, Wv, bv, Qf, Kf, Vf);
  flash_f32<<<dim3(256), 256, 0, stream>>>(Qf, Kf, Vf, Aout);
  mlp1_kernel<<<dim3(4, 256), 256, 0, stream>>>(Aout, W1, b1, Ho);
  act_kernel<<<dim3(2048), 256, 0, stream>>>(Ho, g1, be1, W2, b2, Act);
  physics_kernel<<<dim3(32), 256, 0, stream>>>(obs, Act, out);
}